// Round 1
// 325.472 us; speedup vs baseline: 1.0943x; 1.0943x over previous
//
#include <hip/hip_runtime.h>
#include <hip/hip_bf16.h>
#include <stdint.h>

typedef short bf16x8 __attribute__((ext_vector_type(8)));
typedef float f32x4 __attribute__((ext_vector_type(4)));

#define B_   512
#define N_   256
#define C_   192
#define H_   6
#define D_   32
#define NW_  64

__device__ __forceinline__ uint16_t f2bf(float f) {
    uint32_t u = __builtin_bit_cast(uint32_t, f);
    u += 0x7FFFu + ((u >> 16) & 1u);
    return (uint16_t)(u >> 16);
}

// packed 2xfp32 -> 2xbf16 (v_cvt_pk_bf16_f32 on gfx950)
__device__ __forceinline__ uint32_t pk_bf16(float a, float b) {
    float2 t; t.x = a; t.y = b;
    __hip_bfloat162 h = __float22bfloat162_rn(t);
    uint32_t u;
    __builtin_memcpy(&u, &h, 4);
    return u;
}

__device__ __forceinline__ bf16x8 ld_bf8(const uint16_t* p) {
    uint4 u = *reinterpret_cast<const uint4*>(p);
    return __builtin_bit_cast(bf16x8, u);
}

// ---------------- prep: mask -> AND-selector, weights -> bf16 ----------------
// Also sets *flag=1 iff any mask element is nonzero (enables no-mask fast path).
__global__ void prep_kernel(const float* __restrict__ mask,
                            const float* __restrict__ wqkv,
                            const float* __restrict__ wproj,
                            uint16_t* __restrict__ sel,
                            uint16_t* __restrict__ wqkv_bf,
                            uint16_t* __restrict__ wproj_bf,
                            unsigned* __restrict__ flag) {
    const int64_t NSEL = (int64_t)NW_ * N_ * N_;       // 4194304
    const int64_t NWQ  = 3 * C_ * C_;                  // 110592
    const int64_t NWP  = (int64_t)C_ * C_;             // 36864
    int64_t i = (int64_t)blockIdx.x * blockDim.x + threadIdx.x;
    int64_t stride = (int64_t)gridDim.x * blockDim.x;
    bool nz = false;
    for (; i < NSEL + NWQ + NWP; i += stride) {
        if (i < NSEL) {
            float m = mask[i];
            nz |= (m != 0.0f);
            sel[i] = (m == 0.0f) ? 0xFFFFu : 0u;   // exp(0)=1, exp(-inf)=0
        } else if (i < NSEL + NWQ) {
            int64_t j = i - NSEL;
            wqkv_bf[j] = f2bf(wqkv[j]);
        } else {
            int64_t j = i - NSEL - NWQ;
            wproj_bf[j] = f2bf(wproj[j]);
        }
    }
    if (flag && __any(nz) && ((threadIdx.x & 63) == 0))
        atomicOr(flag, 1u);
}

// ---------------- kernel A: qkv = x @ Wqkv^T, single pass over x ------------
#define SA 200   // x LDS stride (u16)
#define SB 72    // W LDS stride (u16)
__global__ __launch_bounds__(512, 4)
void qkv_kernel(const float* __restrict__ x, const uint16_t* __restrict__ wq,
                uint16_t* __restrict__ qbuf, uint16_t* __restrict__ kbuf,
                uint16_t* __restrict__ vtbuf) {
    __shared__ __align__(16) uint16_t Alds[128 * SA];   // 51200 B
    __shared__ __align__(16) uint16_t Blds[192 * SB];   // 27648 B
    const int tid  = threadIdx.x;
    const int lane = tid & 63;
    const int wv   = tid >> 6;       // 0..7
    const int wrow = wv >> 2;        // 0..1 : which 64 pos-rows
    const int wcol = wv & 3;         // 0..3 : which 48 c-cols
    const int quad = lane >> 4;
    const int l15  = lane & 15;
    const int m0   = blockIdx.x * 128;

    // stage A once: 128x192 fp32 -> bf16 (6144 float4, 12 per thread)
#pragma unroll
    for (int p = 0; p < 12; p++) {
        int f = p * 512 + tid;
        int row = f / 48, c4 = f % 48;
        const float4 v = *reinterpret_cast<const float4*>(
            x + (int64_t)(m0 + row) * 192 + c4 * 4);
        uint2 d;
        d.x = pk_bf16(v.x, v.y);
        d.y = pk_bf16(v.z, v.w);
        *reinterpret_cast<uint2*>(&Alds[row * SA + c4 * 4]) = d;
    }

    // 32^-0.5 * log2(e): attention uses exp2 directly (v_exp_f32 is 2^x)
    const float scale = 0.17677669529663687f * 1.4426950408889634f;

    for (int cb = 0; cb < 3; cb++) {
        f32x4 acc[4][3];   // [x pos-tile][w c-tile]
#pragma unroll
        for (int i = 0; i < 4; i++)
#pragma unroll
            for (int j = 0; j < 3; j++) acc[i][j] = (f32x4)0.f;

        for (int k0 = 0; k0 < 192; k0 += 64) {
            __syncthreads();
#pragma unroll
            for (int p = 0; p < 3; p++) {
                int u = p * 512 + tid;
                int row = u >> 3, c8 = u & 7;
                uint4 w = *reinterpret_cast<const uint4*>(
                    wq + (int64_t)(cb * 192 + row) * 192 + k0 + c8 * 8);
                *reinterpret_cast<uint4*>(&Blds[row * SB + c8 * 8]) = w;
            }
            __syncthreads();
#pragma unroll
            for (int ks = 0; ks < 2; ks++) {
                bf16x8 xf[4], wf[3];
#pragma unroll
                for (int i = 0; i < 4; i++)
                    xf[i] = *reinterpret_cast<const bf16x8*>(
                        &Alds[(wrow * 64 + i * 16 + l15) * SA + k0 + ks * 32 + quad * 8]);
#pragma unroll
                for (int j = 0; j < 3; j++)
                    wf[j] = *reinterpret_cast<const bf16x8*>(
                        &Blds[(wcol * 48 + j * 16 + l15) * SB + ks * 32 + quad * 8]);
                if (cb < 2) {
#pragma unroll
                    for (int i = 0; i < 4; i++)
#pragma unroll
                        for (int j = 0; j < 3; j++)
                            acc[i][j] = __builtin_amdgcn_mfma_f32_16x16x32_bf16(
                                wf[j], xf[i], acc[i][j], 0, 0, 0);
                } else {
#pragma unroll
                    for (int i = 0; i < 4; i++)
#pragma unroll
                        for (int j = 0; j < 3; j++)
                            acc[i][j] = __builtin_amdgcn_mfma_f32_16x16x32_bf16(
                                xf[i], wf[j], acc[i][j], 0, 0, 0);
                }
            }
        }

        // epilogue: 8-byte packed stores
        if (cb < 2) {
            // lane dim = pos, reg dim = c (4 consecutive)
            uint16_t* dst = (cb == 0) ? qbuf : kbuf;
            const float sc = (cb == 0) ? scale : 1.0f;
#pragma unroll
            for (int i = 0; i < 4; i++) {
                int m = m0 + wrow * 64 + i * 16 + l15;
                int b = m >> 8, pos = m & 255;
#pragma unroll
                for (int j = 0; j < 3; j++) {
                    int cbase = wcol * 48 + j * 16 + quad * 4;
                    int h = cbase >> 5, d0 = cbase & 31;
                    int64_t bh = (int64_t)b * H_ + h;
                    uint2 s;
                    s.x = pk_bf16(acc[i][j][0] * sc, acc[i][j][1] * sc);
                    s.y = pk_bf16(acc[i][j][2] * sc, acc[i][j][3] * sc);
                    *reinterpret_cast<uint2*>(&dst[(bh * N_ + pos) * D_ + d0]) = s;
                }
            }
        } else {
            // lane dim = c, reg dim = pos (4 consecutive) -> vT rows
#pragma unroll
            for (int i = 0; i < 4; i++) {
                int m = m0 + wrow * 64 + i * 16 + quad * 4;
                int b = m >> 8, pos0 = m & 255;
#pragma unroll
                for (int j = 0; j < 3; j++) {
                    int c = wcol * 48 + j * 16 + l15;
                    int h = c >> 5, d = c & 31;
                    int64_t bh = (int64_t)b * H_ + h;
                    uint2 s;
                    s.x = pk_bf16(acc[i][j][0], acc[i][j][1]);
                    s.y = pk_bf16(acc[i][j][2], acc[i][j][3]);
                    *reinterpret_cast<uint2*>(&vtbuf[(bh * D_ + d) * N_ + pos0]) = s;
                }
            }
        }
    }
}

// ---------------- kernel B: attention per (b,h,half) -------------------------
// grid 6144, block 256 (4 waves, each owns 32 q-rows). No __syncthreads needed.
// Changes vs prior version:
//   * 32 rows/wave -> sacc 16 regs (was 64), oacc 16, lacc 8: combined reg
//     footprint ~150 -> 3 waves/SIMD (was 2, reg-bound at ~180).
//   * j-tile split into two 32-wide halves; P strip 32x40 u16 per (wave,half)
//     -> LDS 20480 B (was 36864) and stride-40 spreads ds_read_b128 start
//     banks across all 32 banks (stride-72 hit only 8 -> 4.7M conflicts).
//   * K prefetched one jc ahead; V + sel hoisted to top of jc (latency hides
//     under QK-MFMA + exp).
//   * exp2 direct (log2e pre-folded into Q scale), saves 1 v_mul per element.
//   * no-mask fast path: skip all sel loads when flag==0 (mask all-zero).
//   * s_setprio(1) around MFMA clusters.
__global__ __launch_bounds__(256, 3)
void attn_kernel(const uint16_t* __restrict__ qbuf, const uint16_t* __restrict__ kbuf,
                 const uint16_t* __restrict__ vtbuf, const uint16_t* __restrict__ sel,
                 const unsigned* __restrict__ flag,
                 uint16_t* __restrict__ aout) {
    __shared__ __align__(16) uint16_t Plds[4 * 2 * 32 * 40];   // 20480 B
    const int bi = blockIdx.x;
    const int h  = bi % 6;
    const int r_ = bi / 6;
    const int ih = r_ & 1;                  // which 128-row half of the 256 q-rows
    const int g  = (r_ >> 1) & 7;
    const int w  = r_ >> 4;                 // same-w blocks adjacent -> L2 locality for sel
    const int b  = g * 64 + w;              // b % 64 == w
    const int tid  = threadIdx.x;
    const int lane = tid & 63;
    const int wv   = tid >> 6;
    const int quad = lane >> 4;
    const int l15  = lane & 15;
    const int i0   = ih * 128 + wv * 32;
    const bool hasmask = flag ? (*flag != 0u) : true;
    const int64_t bh = (int64_t)b * H_ + h;
    const uint16_t* qB = qbuf  + bh * N_ * D_;
    const uint16_t* kB = kbuf  + bh * N_ * D_;
    const uint16_t* vB = vtbuf + bh * D_ * N_;
    const uint16_t* sB = sel   + (int64_t)w * N_ * N_;
    uint16_t* Pw = &Plds[wv * 2 * 32 * 40];

    // Q fragments (used as B-operand: n=lane&15 -> i, k=quad*8+e -> d)
    bf16x8 qf[2];
#pragma unroll
    for (int it = 0; it < 2; it++)
        qf[it] = ld_bf8(&qB[(i0 + it * 16 + l15) * D_ + quad * 8]);

    f32x4 oacc[2][2];
    f32x4 lacc[2];
#pragma unroll
    for (int mt = 0; mt < 2; mt++) {
        oacc[mt][0] = (f32x4)0.f; oacc[mt][1] = (f32x4)0.f; lacc[mt] = (f32x4)0.f;
    }
    bf16x8 ones;
#pragma unroll
    for (int e = 0; e < 8; e++) ones[e] = (short)0x3F80;   // bf16 1.0

    // K prologue (jc=0)
    bf16x8 kf[4];
#pragma unroll
    for (int jt = 0; jt < 4; jt++)
        kf[jt] = ld_bf8(&kB[(jt * 16 + l15) * D_ + quad * 8]);

    for (int jc = 0; jc < 4; jc++) {
        const int j0 = jc * 64;

        // prefetch next K tile (hidden under this jc's compute)
        bf16x8 kfn[4];
        if (jc < 3) {
#pragma unroll
            for (int jt = 0; jt < 4; jt++)
                kfn[jt] = ld_bf8(&kB[(j0 + 64 + jt * 16 + l15) * D_ + quad * 8]);
        }

        // V fragments for both halves (B-layout: n=lane&15 -> d, k -> j)
        bf16x8 vf[2][2];
#pragma unroll
        for (int hf = 0; hf < 2; hf++)
#pragma unroll
            for (int nt = 0; nt < 2; nt++)
                vf[hf][nt] = ld_bf8(&vB[(nt * 16 + l15) * N_ + j0 + hf * 32 + quad * 8]);

        // selector fragments, issued early so L2 latency hides under QK+exp
        uint4 sv[2][2];
        if (hasmask) {
#pragma unroll
            for (int hf = 0; hf < 2; hf++)
#pragma unroll
                for (int mt = 0; mt < 2; mt++)
                    sv[hf][mt] = *reinterpret_cast<const uint4*>(
                        &sB[(int64_t)(i0 + mt * 16 + l15) * N_ + j0 + hf * 32 + quad * 8]);
        } else {
#pragma unroll
            for (int hf = 0; hf < 2; hf++)
#pragma unroll
                for (int mt = 0; mt < 2; mt++)
                    sv[hf][mt] = make_uint4(~0u, ~0u, ~0u, ~0u);
        }

#pragma unroll
        for (int hf = 0; hf < 2; hf++) {
            // S^T = K Q^T : D[j][i], C-layout col=i=lane&15, row=j=quad*4+r
            f32x4 sacc[2][2];   // [jt2][it]
#pragma unroll
            for (int jt2 = 0; jt2 < 2; jt2++)
#pragma unroll
                for (int it = 0; it < 2; it++) sacc[jt2][it] = (f32x4)0.f;
            __builtin_amdgcn_s_setprio(1);
#pragma unroll
            for (int jt2 = 0; jt2 < 2; jt2++)
#pragma unroll
                for (int it = 0; it < 2; it++)
                    sacc[jt2][it] = __builtin_amdgcn_mfma_f32_16x16x32_bf16(
                        kf[hf * 2 + jt2], qf[it], sacc[jt2][it], 0, 0, 0);
            __builtin_amdgcn_s_setprio(0);

            // P^T -> P strip: lane holds 4 consecutive j for i=it*16+l15
            uint16_t* Ph = Pw + hf * (32 * 40);
#pragma unroll
            for (int it = 0; it < 2; it++)
#pragma unroll
                for (int jt2 = 0; jt2 < 2; jt2++) {
                    f32x4 s = sacc[jt2][it];
                    uint2 d;
                    d.x = pk_bf16(__builtin_amdgcn_exp2f(s[0]),
                                  __builtin_amdgcn_exp2f(s[1]));
                    d.y = pk_bf16(__builtin_amdgcn_exp2f(s[2]),
                                  __builtin_amdgcn_exp2f(s[3]));
                    *reinterpret_cast<uint2*>(
                        &Ph[(it * 16 + l15) * 40 + jt2 * 16 + quad * 4]) = d;
                }

            // PV + ones-MFMA row-sum, mask AND applied on P fragments
#pragma unroll
            for (int mt = 0; mt < 2; mt++) {
                uint4 p = *reinterpret_cast<const uint4*>(
                    &Ph[(mt * 16 + l15) * 40 + quad * 8]);
                p.x &= sv[hf][mt].x; p.y &= sv[hf][mt].y;
                p.z &= sv[hf][mt].z; p.w &= sv[hf][mt].w;
                bf16x8 pa = __builtin_bit_cast(bf16x8, p);
                __builtin_amdgcn_s_setprio(1);
                oacc[mt][0] = __builtin_amdgcn_mfma_f32_16x16x32_bf16(pa, vf[hf][0], oacc[mt][0], 0, 0, 0);
                oacc[mt][1] = __builtin_amdgcn_mfma_f32_16x16x32_bf16(pa, vf[hf][1], oacc[mt][1], 0, 0, 0);
                lacc[mt]    = __builtin_amdgcn_mfma_f32_16x16x32_bf16(pa, ones,      lacc[mt],    0, 0, 0);
                __builtin_amdgcn_s_setprio(0);
            }
        }

        if (jc < 3) {
#pragma unroll
            for (int jt = 0; jt < 4; jt++) kf[jt] = kfn[jt];
        }
    }

    // normalize (l is in the same C-layout as O: every lane holds its row's sum)
#pragma unroll
    for (int mt = 0; mt < 2; mt++)
#pragma unroll
        for (int r4 = 0; r4 < 4; r4++) {
            float inv = 1.0f / lacc[mt][r4];
            int i = i0 + mt * 16 + quad * 4 + r4;
#pragma unroll
            for (int nt = 0; nt < 2; nt++) {
                float v = oacc[mt][nt][r4] * inv;
                aout[((int64_t)b * N_ + i) * C_ + h * 32 + nt * 16 + l15] = f2bf(v);
            }
        }
}

// ---------------- kernel C: out = attn_out @ Wproj^T + b ---------------------
// grid 1024, block 512
__global__ __launch_bounds__(512, 2)
void proj_kernel(const uint16_t* __restrict__ a, const uint16_t* __restrict__ wp,
                 const float* __restrict__ bias, float* __restrict__ out) {
    __shared__ __align__(16) uint16_t Alds[128 * 72];
    __shared__ __align__(16) uint16_t Blds[192 * 72];
    const int tid  = threadIdx.x;
    const int lane = tid & 63;
    const int wv   = tid >> 6;
    const int wm   = wv >> 2;
    const int wn   = wv & 3;
    const int quad = lane >> 4;
    const int l15  = lane & 15;
    const int m0   = blockIdx.x * 128;

    f32x4 acc[4][3];
#pragma unroll
    for (int x = 0; x < 4; x++)
#pragma unroll
        for (int y = 0; y < 3; y++) acc[x][y] = (f32x4)0.f;

    for (int k0 = 0; k0 < 192; k0 += 64) {
        __syncthreads();
#pragma unroll
        for (int p = 0; p < 2; p++) {
            int u = tid + p * 512;                 // 1024 ushort8
            int row = u >> 3, c8 = u & 7;
            uint4 v = *reinterpret_cast<const uint4*>(
                a + (int64_t)(m0 + row) * 192 + k0 + c8 * 8);
            *reinterpret_cast<uint4*>(&Alds[row * 72 + c8 * 8]) = v;
        }
#pragma unroll
        for (int p = 0; p < 3; p++) {
            int u = tid + p * 512;                 // 1536 ushort8
            int row = u >> 3, c8 = u & 7;
            uint4 v = *reinterpret_cast<const uint4*>(
                wp + (int64_t)row * 192 + k0 + c8 * 8);
            *reinterpret_cast<uint4*>(&Blds[row * 72 + c8 * 8]) = v;
        }
        __syncthreads();
#pragma unroll
        for (int ks = 0; ks < 2; ks++) {
            bf16x8 af[4], bfr[3];
#pragma unroll
            for (int mt = 0; mt < 4; mt++)
                af[mt] = *reinterpret_cast<const bf16x8*>(
                    &Alds[(wm * 64 + mt * 16 + l15) * 72 + ks * 32 + quad * 8]);
#pragma unroll
            for (int nt = 0; nt < 3; nt++)
                bfr[nt] = *reinterpret_cast<const bf16x8*>(
                    &Blds[(wn * 48 + nt * 16 + l15) * 72 + ks * 32 + quad * 8]);
#pragma unroll
            for (int mt = 0; mt < 4; mt++)
#pragma unroll
                for (int nt = 0; nt < 3; nt++)
                    acc[mt][nt] = __builtin_amdgcn_mfma_f32_16x16x32_bf16(
                        af[mt], bfr[nt], acc[mt][nt], 0, 0, 0);
        }
    }
    float bv[3];
#pragma unroll
    for (int nt = 0; nt < 3; nt++) bv[nt] = bias[wn * 48 + nt * 16 + l15];
#pragma unroll
    for (int mt = 0; mt < 4; mt++)
#pragma unroll
        for (int r = 0; r < 4; r++) {
            int m = m0 + wm * 64 + mt * 16 + quad * 4 + r;
#pragma unroll
            for (int nt = 0; nt < 3; nt++) {
                int col = wn * 48 + nt * 16 + l15;
                out[(int64_t)m * 192 + col] = acc[mt][nt][r] + bv[nt];
            }
        }
}

extern "C" void kernel_launch(void* const* d_in, const int* in_sizes, int n_in,
                              void* d_out, int out_size, void* d_ws, size_t ws_size,
                              hipStream_t stream) {
    const float* x     = (const float*)d_in[0];
    const float* mask  = (const float*)d_in[1];
    const float* wqkv  = (const float*)d_in[2];
    const float* wproj = (const float*)d_in[3];
    const float* bproj = (const float*)d_in[4];
    float* out = (float*)d_out;

    // q,k (bf16) live in d_out (exactly 2 x 50331648 B = out bytes); overwritten by proj at the end.
    uint16_t* qbuf = (uint16_t*)d_out;
    uint16_t* kbuf = qbuf + 25165824;
    char* ws = (char*)d_ws;
    uint16_t* vtbuf = (uint16_t*)(ws);                 // 50331648 B
    uint16_t* aout  = (uint16_t*)(ws + 50331648);      // 50331648 B
    uint16_t* sel   = (uint16_t*)(ws + 100663296);     // 8388608 B
    uint16_t* wq_bf = (uint16_t*)(ws + 109051904);     // 221184 B
    uint16_t* wp_bf = (uint16_t*)(ws + 109273088);     // 73728 B
    unsigned* flag  = nullptr;                         // 4 B mask-nonzero flag
    if (ws_size >= 109346816 + 4)
        flag = (unsigned*)(ws + 109346816);

    if (flag) hipMemsetAsync(flag, 0, 4, stream);
    prep_kernel<<<4096, 256, 0, stream>>>(mask, wqkv, wproj, sel, wq_bf, wp_bf, flag);
    qkv_kernel<<<1024, 512, 0, stream>>>(x, wq_bf, qbuf, kbuf, vtbuf);
    attn_kernel<<<6144, 256, 0, stream>>>(qbuf, kbuf, vtbuf, sel, flag, aout);
    proj_kernel<<<1024, 512, 0, stream>>>(aout, wp_bf, bproj, out);
}